// Round 4
// baseline (1429.474 us; speedup 1.0000x reference)
//
#include <hip/hip_runtime.h>

#define T_SEQ 2048
#define NH    16
#define D_NOPE 128
#define D_ROPE 64
#define D_V   128
#define RANK  512
#define D_QIN 1536
#define D_HID 7168
#define D_QK  576           // RANK + D_ROPE
#define QF_N  3072          // NH*(D_NOPE+D_ROPE)
#define ATT_SCALE 0.07216878364870322f   // (192)^-0.5

typedef float  f32x4  __attribute__((ext_vector_type(4)));
typedef __bf16 bf16x8 __attribute__((ext_vector_type(8)));

__device__ __forceinline__ unsigned short f2bf(float x){
  union{float f; unsigned u;} v; v.f = x;
  return (unsigned short)((v.u + 0x7fffu + ((v.u >> 16) & 1u)) >> 16);
}
__device__ __forceinline__ float bf2f(unsigned short b){
  union{unsigned u; float f;} v; v.u = ((unsigned)b) << 16; return v.f;
}
__device__ __forceinline__ bf16x8 ld_frag(const unsigned short* p){
  union{ uint4 u; bf16x8 v; } w; w.u = *(const uint4*)p; return w.v;
}
// async global->LDS, 16B per lane; LDS side must be uniform + lane*16 (it is).
__device__ __forceinline__ void gload_lds16(const unsigned short* g, unsigned short* l){
  __builtin_amdgcn_global_load_lds(
      (const __attribute__((address_space(1))) unsigned int*)g,
      (__attribute__((address_space(3))) unsigned int*)l, 16, 0, 0);
}

// ---------------- fp32 -> bf16 bulk convert ----------------
__global__ void cvt_bf16_kernel(const float* __restrict__ in, unsigned short* __restrict__ out, long n){
  long i = ((long)blockIdx.x * blockDim.x + threadIdx.x) * 4;
  if (i + 3 < n){
    float4 f = *(const float4*)(in + i);
    ushort4 o; o.x = f2bf(f.x); o.y = f2bf(f.y); o.z = f2bf(f.z); o.w = f2bf(f.w);
    *(ushort4*)(out + i) = o;
  }
}

// ---------------- k_cat = [bf16(k_c) | rope(k_pe)] : (T, 576) ----------------
__global__ void prep_kcat_kernel(const float* __restrict__ kc, const float* __restrict__ kpe,
                                 const int* __restrict__ pos, const float* __restrict__ cosc,
                                 const float* __restrict__ sinc, unsigned short* __restrict__ kcat){
  int t = blockIdx.x; int tid = threadIdx.x;
  for (int c = tid; c < RANK; c += 256)
    kcat[(long)t * D_QK + c] = f2bf(kc[(long)t * RANK + c]);
  if (tid < 32){
    int p = pos[t];
    float c = cosc[p * 32 + tid], s = sinc[p * 32 + tid];
    float x1 = kpe[(long)t * D_ROPE + tid];
    float x2 = kpe[(long)t * D_ROPE + 32 + tid];
    kcat[(long)t * D_QK + RANK + tid]      = f2bf(x1 * c - x2 * s);
    kcat[(long)t * D_QK + RANK + 32 + tid] = f2bf(x2 * c + x1 * s);
  }
}

// ---------------- Vt = bf16(k_c)^T : (512, T) ----------------
__global__ void transpose_vt_kernel(const float* __restrict__ kc, unsigned short* __restrict__ vt){
  __shared__ unsigned short tile[64][65];
  int bi = blockIdx.x, bj = blockIdx.y, tid = threadIdx.x;
  for (int c = tid; c < 4096; c += 256){
    int i = c >> 6, j = c & 63;
    tile[i][j] = f2bf(kc[(long)(bi * 64 + i) * RANK + bj * 64 + j]);
  }
  __syncthreads();
  for (int c = tid; c < 4096; c += 256){
    int j = c >> 6, i = c & 63;
    vt[(long)(bj * 64 + j) * T_SEQ + bi * 64 + i] = tile[i][j];
  }
}

// ---------------- wukt[h][r][d] = bf16(kvb[h*256+d][r]) ----------------
__global__ void prep_wukt_kernel(const float* __restrict__ kvb, unsigned short* __restrict__ wukt){
  __shared__ unsigned short tile[64][65];
  int h = blockIdx.x, db = blockIdx.y, rb = blockIdx.z, tid = threadIdx.x;
  for (int c = tid; c < 4096; c += 256){
    int i = c >> 6, j = c & 63;   // i: d within 64, j: r within 64
    tile[i][j] = f2bf(kvb[(long)(h * 256 + db * 64 + i) * RANK + rb * 64 + j]);
  }
  __syncthreads();
  for (int c = tid; c < 4096; c += 256){
    int j = c >> 6, i = c & 63;
    wukt[(long)h * RANK * D_NOPE + (long)(rb * 64 + j) * D_NOPE + db * 64 + i] = tile[i][j];
  }
}

// ---------------- rope on q_pe: qf(t, h*192+128..191) -> qcat[h][t][512..575] ----------------
__global__ void rope_q_kernel(const unsigned short* __restrict__ qf, const int* __restrict__ pos,
                              const float* __restrict__ cosc, const float* __restrict__ sinc,
                              unsigned short* __restrict__ qcat){
  int t = blockIdx.x; int tid = threadIdx.x;
  int p = pos[t];
  for (int w = tid; w < 512; w += 256){
    int h = w >> 5, i = w & 31;
    float c = cosc[p * 32 + i], s = sinc[p * 32 + i];
    float x1 = bf2f(qf[(long)t * QF_N + h * 192 + 128 + i]);
    float x2 = bf2f(qf[(long)t * QF_N + h * 192 + 128 + 32 + i]);
    long base = (long)h * T_SEQ * D_QK + (long)t * D_QK + RANK;
    qcat[base + i]      = f2bf(x1 * c - x2 * s);
    qcat[base + 32 + i] = f2bf(x2 * c + x1 * s);
  }
}

// ---------------- generic NT bf16 GEMM: C = A(MxK) * B(NxK)^T (async LDS staging) ----------------
template<int OUT_BF16>
__global__ __launch_bounds__(256, 2) void gemm_nt_kernel(
    const unsigned short* __restrict__ A, long lda, long sA,
    const unsigned short* __restrict__ B, long ldb, long sB,
    void* __restrict__ Cv, long ldc, long sC,
    int M, int N, int K)
{
  const int bz = blockIdx.z;
  A += (long)bz * sA;
  B += (long)bz * sB;
  const int m0 = blockIdx.x * 128;
  const int n0 = blockIdx.y * 128;
  const int tid = threadIdx.x;
  const int lane = tid & 63, wave = tid >> 6;
  const int quad = lane >> 4, l16 = lane & 15;
  const int wm = wave & 1, wn = wave >> 1;

  __shared__ __align__(16) unsigned short As[128 * 32];
  __shared__ __align__(16) unsigned short Bs[128 * 32];

  f32x4 acc[4][4];
  #pragma unroll
  for (int mt = 0; mt < 4; ++mt)
    #pragma unroll
    for (int nt = 0; nt < 4; ++nt)
      acc[mt][nt] = (f32x4){0.f, 0.f, 0.f, 0.f};

  for (int k0 = 0; k0 < K; k0 += 32){
    __syncthreads();
    #pragma unroll
    for (int i = 0; i < 2; ++i){
      int c = i * 256 + tid;
      int row = c >> 2, col = (c & 3) * 8;
      gload_lds16(A + (long)(m0 + row) * lda + k0 + col, &As[c * 8]);
      gload_lds16(B + (long)(n0 + row) * ldb + k0 + col, &Bs[c * 8]);
    }
    __syncthreads();
    bf16x8 af[4], bg[4];
    #pragma unroll
    for (int mt = 0; mt < 4; ++mt) af[mt] = ld_frag(&As[(wm * 64 + mt * 16 + l16) * 32 + quad * 8]);
    #pragma unroll
    for (int nt = 0; nt < 4; ++nt) bg[nt] = ld_frag(&Bs[(wn * 64 + nt * 16 + l16) * 32 + quad * 8]);
    #pragma unroll
    for (int mt = 0; mt < 4; ++mt)
      #pragma unroll
      for (int nt = 0; nt < 4; ++nt)
        acc[mt][nt] = __builtin_amdgcn_mfma_f32_16x16x32_bf16(af[mt], bg[nt], acc[mt][nt], 0, 0, 0);
  }

  if (OUT_BF16){
    unsigned short* C = (unsigned short*)Cv + (long)bz * sC;
    #pragma unroll
    for (int mt = 0; mt < 4; ++mt)
      #pragma unroll
      for (int nt = 0; nt < 4; ++nt)
        #pragma unroll
        for (int r = 0; r < 4; ++r)
          C[(long)(m0 + wm * 64 + mt * 16 + quad * 4 + r) * ldc + n0 + wn * 64 + nt * 16 + l16] =
              f2bf(acc[mt][nt][r]);
  } else {
    float* C = (float*)Cv + (long)bz * sC;
    #pragma unroll
    for (int mt = 0; mt < 4; ++mt)
      #pragma unroll
      for (int nt = 0; nt < 4; ++nt)
        #pragma unroll
        for (int r = 0; r < 4; ++r)
          C[(long)(m0 + wm * 64 + mt * 16 + quad * 4 + r) * ldc + n0 + wn * 64 + nt * 16 + l16] =
              acc[mt][nt][r];
  }
}

// ---------------- causal MQA flash attention, wave-autonomous softmax, v-split=4 ----------------
// Q: qcat [NH][T][576], K: kcat [T][576], V^T: vt [512][T], out: olat [NH][T][512]
// Grid (NH, 32 tiles, 4 v-quarters). Block: 4 waves; wave w owns rows t0+16w..+15.
// oacc = 16 rows x 128 v-dims = 32 regs -> total ~165 regs -> 3 waves/SIMD (matches
// LDS limit of 3 blocks/CU at 42.5 KB). Next K-tile prefetched into VGPRs at iter
// start so its latency overlaps QK+softmax+PV; Ks written between barriers (a),(b).
__global__ __launch_bounds__(256, 3) void attn_kernel(
    const unsigned short* __restrict__ qcat,
    const unsigned short* __restrict__ kcat,
    const unsigned short* __restrict__ vt,
    unsigned short* __restrict__ olat)
{
  const int h = blockIdx.x;
  const int ti = (int)gridDim.y - 1 - (int)blockIdx.y;   // longest blocks first
  const int vz = blockIdx.z;
  const int t0 = ti * 64;
  const int tid = threadIdx.x;
  const int lane = tid & 63, wave = tid >> 6;
  const int quad = lane >> 4, l16 = lane & 15;
  const int t0w = t0 + wave * 16;

  __shared__ __align__(16) unsigned short Ks[32 * 584];    // stride 584: 2-way-free b128 reads
  __shared__ __align__(16) unsigned short Pw[4][16 * 40];  // per-wave P buffer

  const unsigned short* vbase = vt + (long)(vz * 128) * T_SEQ;

  // per-lane staging offsets, computed once (chunk i covers flat 16B-unit i*256+tid)
  int goff[9], loff[9];
  #pragma unroll
  for (int i = 0; i < 9; ++i){
    int fc = i * 256 + tid;
    int r = fc / 72, c = fc - r * 72;
    goff[i] = r * D_QK + c * 8;
    loff[i] = r * 584 + c * 8;
  }

  // Q fragments in registers (A-layout: m=l16, k=quad*8+j), 18 x 32-dim chunks = 36 VGPRs
  bf16x8 qf[18];
  {
    const unsigned short* qrow = qcat + (long)h * T_SEQ * D_QK + (long)(t0w + l16) * D_QK;
    #pragma unroll
    for (int kk = 0; kk < 18; ++kk) qf[kk] = ld_frag(qrow + kk * 32 + quad * 8);
  }

  f32x4 oacc[8];   // 16 rows x 128 v-dims = 32 regs
  #pragma unroll
  for (int ct = 0; ct < 8; ++ct) oacc[ct] = (f32x4){0.f, 0.f, 0.f, 0.f};
  float m_run[4], l_run[4];
  #pragma unroll
  for (int r = 0; r < 4; ++r){ m_run[r] = -3e38f; l_run[r] = 0.f; }

  const int niter = 2 * (ti + 1);

  // initial stage (VGPR roundtrip)
  {
    uint4 kv[9];
    #pragma unroll
    for (int i = 0; i < 9; ++i) kv[i] = *(const uint4*)(kcat + goff[i]);
    #pragma unroll
    for (int i = 0; i < 9; ++i) *(uint4*)(&Ks[loff[i]]) = kv[i];
  }
  __syncthreads();

  for (int it = 0; it < niter; ++it){
    const int s0 = it * 32;

    // ---- prefetch next K-tile into VGPRs (latency hidden under QK/softmax/PV) ----
    uint4 kv[9];
    const bool more = (it + 1 < niter);
    if (more){
      const unsigned short* kb = kcat + (long)(s0 + 32) * D_QK;
      #pragma unroll
      for (int i = 0; i < 9; ++i) kv[i] = *(const uint4*)(kb + goff[i]);
    }

    // ---- S = Q K^T (16 rows x 32 keys per wave) ----
    f32x4 sacc0 = (f32x4){0.f,0.f,0.f,0.f}, sacc1 = (f32x4){0.f,0.f,0.f,0.f};
    #pragma unroll
    for (int kk = 0; kk < 18; ++kk){
      bf16x8 b0 = ld_frag(&Ks[l16 * 584 + kk * 32 + quad * 8]);
      bf16x8 b1 = ld_frag(&Ks[(16 + l16) * 584 + kk * 32 + quad * 8]);
      sacc0 = __builtin_amdgcn_mfma_f32_16x16x32_bf16(qf[kk], b0, sacc0, 0, 0, 0);
      sacc1 = __builtin_amdgcn_mfma_f32_16x16x32_bf16(qf[kk], b1, sacc1, 0, 0, 0);
    }
    __syncthreads();     // (a) all waves done reading Ks

    // ---- wave-local online softmax ----
    float sv[2][4], mr[4];
    #pragma unroll
    for (int r = 0; r < 4; ++r){
      int row = t0w + quad * 4 + r;
      float v0 = sacc0[r] * ATT_SCALE;
      float v1 = sacc1[r] * ATT_SCALE;
      if (s0 + l16 > row)      v0 = -3e38f;
      if (s0 + 16 + l16 > row) v1 = -3e38f;
      sv[0][r] = v0; sv[1][r] = v1; mr[r] = fmaxf(v0, v1);
    }
    #pragma unroll
    for (int d = 1; d < 16; d <<= 1)
      #pragma unroll
      for (int r = 0; r < 4; ++r) mr[r] = fmaxf(mr[r], __shfl_xor(mr[r], d, 64));
    float alpha[4], ps[4];
    #pragma unroll
    for (int r = 0; r < 4; ++r){
      float mn = fmaxf(m_run[r], mr[r]);
      alpha[r] = __expf(m_run[r] - mn);
      m_run[r] = mn;
      float p0 = __expf(sv[0][r] - mn);
      float p1 = __expf(sv[1][r] - mn);
      Pw[wave][(quad * 4 + r) * 40 + l16]      = f2bf(p0);
      Pw[wave][(quad * 4 + r) * 40 + 16 + l16] = f2bf(p1);
      ps[r] = p0 + p1;
    }
    #pragma unroll
    for (int d = 1; d < 16; d <<= 1)
      #pragma unroll
      for (int r = 0; r < 4; ++r) ps[r] += __shfl_xor(ps[r], d, 64);
    #pragma unroll
    for (int r = 0; r < 4; ++r) l_run[r] = alpha[r] * l_run[r] + ps[r];

    // rescale O
    #pragma unroll
    for (int ct = 0; ct < 8; ++ct)
      #pragma unroll
      for (int r = 0; r < 4; ++r) oacc[ct][r] *= alpha[r];

    // P write -> A-frag read is wave-local cross-lane: drain DS pipe
    __builtin_amdgcn_s_waitcnt(0xC07F);   // lgkmcnt(0)

    bf16x8 pa = ld_frag(&Pw[wave][l16 * 40 + quad * 8]);
    #pragma unroll
    for (int ct = 0; ct < 8; ++ct){
      bf16x8 bv = ld_frag(vbase + (long)(ct * 16 + l16) * T_SEQ + s0 + quad * 8);
      oacc[ct] = __builtin_amdgcn_mfma_f32_16x16x32_bf16(pa, bv, oacc[ct], 0, 0, 0);
    }

    // ---- write prefetched tile into Ks ----
    if (more){
      #pragma unroll
      for (int i = 0; i < 9; ++i) *(uint4*)(&Ks[loff[i]]) = kv[i];
    }
    __syncthreads();     // (b) next tile staged
  }

  // ---- epilogue ----
  float inv[4];
  #pragma unroll
  for (int r = 0; r < 4; ++r) inv[r] = 1.0f / l_run[r];
  #pragma unroll
  for (int ct = 0; ct < 8; ++ct)
    #pragma unroll
    for (int r = 0; r < 4; ++r){
      int row = t0w + quad * 4 + r;
      olat[(long)h * T_SEQ * RANK + (long)row * RANK + vz * 128 + ct * 16 + l16] =
          f2bf(oacc[ct][r] * inv[r]);
    }
}

// ---------------- host launcher ----------------
extern "C" void kernel_launch(void* const* d_in, const int* in_sizes, int n_in,
                              void* d_out, int out_size, void* d_ws, size_t ws_size,
                              hipStream_t stream){
  const float* q    = (const float*)d_in[0];
  const float* kc   = (const float*)d_in[1];
  const float* kpe  = (const float*)d_in[2];
  const int*   pos  = (const int*)d_in[3];
  const float* wq   = (const float*)d_in[4];
  const float* kvb  = (const float*)d_in[5];
  const float* wo   = (const float*)d_in[6];
  const float* cosc = (const float*)d_in[7];
  const float* sinc = (const float*)d_in[8];
  float* out = (float*)d_out;

  char* ws = (char*)d_ws;
  size_t off = 0;
  auto alloc_us = [&](long nelem) -> unsigned short* {
    unsigned short* p = (unsigned short*)(ws + off);
    off += ((size_t)nelem * 2 + 255) & ~(size_t)255;
    return p;
  };
  unsigned short* q_bf   = alloc_us((long)T_SEQ * D_QIN);          // 2048x1536
  unsigned short* wq_bf  = alloc_us((long)QF_N * D_QIN);           // 3072x1536
  unsigned short* kvb_bf = alloc_us((long)NH * 256 * RANK);        // 4096x512
  unsigned short* wukt   = alloc_us((long)NH * RANK * D_NOPE);     // 16x512x128
  unsigned short* wo_bf  = alloc_us((long)D_HID * NH * D_V);       // 7168x2048
  unsigned short* kcat   = alloc_us((long)T_SEQ * D_QK);           // 2048x576
  unsigned short* vt     = alloc_us((long)RANK * T_SEQ);           // 512x2048
  unsigned short* qf_bf  = alloc_us((long)T_SEQ * QF_N);           // 2048x3072
  unsigned short* qcat   = alloc_us((long)NH * T_SEQ * D_QK);      // 16x2048x576
  unsigned short* olat   = alloc_us((long)NH * T_SEQ * RANK);      // 16x2048x512
  unsigned short* o_mid  = alloc_us((long)T_SEQ * NH * D_V);       // 2048x2048

  // conversions
  {
    long n;
    n = (long)T_SEQ * D_QIN;
    cvt_bf16_kernel<<<dim3((unsigned)(n / 1024)), 256, 0, stream>>>(q, q_bf, n);
    n = (long)QF_N * D_QIN;
    cvt_bf16_kernel<<<dim3((unsigned)(n / 1024)), 256, 0, stream>>>(wq, wq_bf, n);
    n = (long)NH * 256 * RANK;
    cvt_bf16_kernel<<<dim3((unsigned)(n / 1024)), 256, 0, stream>>>(kvb, kvb_bf, n);
    n = (long)D_HID * NH * D_V;
    cvt_bf16_kernel<<<dim3((unsigned)(n / 1024)), 256, 0, stream>>>(wo, wo_bf, n);
  }
  prep_kcat_kernel<<<dim3(T_SEQ), 256, 0, stream>>>(kc, kpe, pos, cosc, sinc, kcat);
  transpose_vt_kernel<<<dim3(T_SEQ / 64, RANK / 64), 256, 0, stream>>>(kc, vt);
  prep_wukt_kernel<<<dim3(NH, D_NOPE / 64, RANK / 64), 256, 0, stream>>>(kvb, wukt);

  // G1: qf = q @ wq^T  (2048 x 3072, K=1536), bf16 out
  gemm_nt_kernel<1><<<dim3(T_SEQ / 128, QF_N / 128), 256, 0, stream>>>(
      q_bf, D_QIN, 0, wq_bf, D_QIN, 0, (void*)qf_bf, QF_N, 0, T_SEQ, QF_N, D_QIN);

  rope_q_kernel<<<dim3(T_SEQ), 256, 0, stream>>>(qf_bf, pos, cosc, sinc, qcat);

  // G2 (batched over heads): qcat[h][:, 0:512] = q_nope_h @ wukt_h^T  (2048x512, K=128)
  gemm_nt_kernel<1><<<dim3(T_SEQ / 128, RANK / 128, NH), 256, 0, stream>>>(
      qf_bf, QF_N, 192,
      wukt, D_NOPE, (long)RANK * D_NOPE,
      (void*)qcat, D_QK, (long)T_SEQ * D_QK,
      T_SEQ, RANK, D_NOPE);

  // attention: grid (head, tile, v-quarter), longest tiles dispatched first
  attn_kernel<<<dim3(NH, T_SEQ / 64, 4), 256, 0, stream>>>(qcat, kcat, vt, olat);

  // G3 (batched): o_mid[:, h*128:(h+1)*128] = olat_h @ w_uv_h^T  (2048x128, K=512)
  gemm_nt_kernel<1><<<dim3(T_SEQ / 128, D_V / 128, NH), 256, 0, stream>>>(
      olat, RANK, (long)T_SEQ * RANK,
      kvb_bf + (long)128 * RANK, RANK, (long)256 * RANK,
      (void*)o_mid, (long)NH * D_V, (long)D_V,
      T_SEQ, D_V, RANK);

  // G4: out = o_mid @ wo^T  (2048 x 7168, K=2048), fp32 out
  gemm_nt_kernel<0><<<dim3(T_SEQ / 128, D_HID / 128), 256, 0, stream>>>(
      o_mid, (long)NH * D_V, 0, wo_bf, (long)NH * D_V, 0, (void*)out, D_HID, 0,
      T_SEQ, D_HID, (long)NH * D_V);
}

// Round 5
// 868.321 us; speedup vs baseline: 1.6462x; 1.6462x over previous
//
#include <hip/hip_runtime.h>

#define T_SEQ 2048
#define NH    16
#define D_NOPE 128
#define D_ROPE 64
#define D_V   128
#define RANK  512
#define D_QIN 1536
#define D_HID 7168
#define D_QK  576           // RANK + D_ROPE
#define QF_N  3072          // NH*(D_NOPE+D_ROPE)
#define ATT_SCALE 0.07216878364870322f   // (192)^-0.5

typedef float  f32x4  __attribute__((ext_vector_type(4)));
typedef __bf16 bf16x8 __attribute__((ext_vector_type(8)));

__device__ __forceinline__ unsigned short f2bf(float x){
  union{float f; unsigned u;} v; v.f = x;
  return (unsigned short)((v.u + 0x7fffu + ((v.u >> 16) & 1u)) >> 16);
}
__device__ __forceinline__ float bf2f(unsigned short b){
  union{unsigned u; float f;} v; v.u = ((unsigned)b) << 16; return v.f;
}
__device__ __forceinline__ bf16x8 ld_frag(const unsigned short* p){
  union{ uint4 u; bf16x8 v; } w; w.u = *(const uint4*)p; return w.v;
}
__device__ __forceinline__ bf16x8 ones_frag(){
  union{ uint4 u; bf16x8 v; } w;
  w.u = make_uint4(0x3F803F80u, 0x3F803F80u, 0x3F803F80u, 0x3F803F80u);
  return w.v;
}
// async global->LDS, 16B per lane; LDS side must be uniform + lane*16 (it is).
__device__ __forceinline__ void gload_lds16(const unsigned short* g, unsigned short* l){
  __builtin_amdgcn_global_load_lds(
      (const __attribute__((address_space(1))) unsigned int*)g,
      (__attribute__((address_space(3))) unsigned int*)l, 16, 0, 0);
}

// ---------------- fp32 -> bf16 bulk convert ----------------
__global__ void cvt_bf16_kernel(const float* __restrict__ in, unsigned short* __restrict__ out, long n){
  long i = ((long)blockIdx.x * blockDim.x + threadIdx.x) * 4;
  if (i + 3 < n){
    float4 f = *(const float4*)(in + i);
    ushort4 o; o.x = f2bf(f.x); o.y = f2bf(f.y); o.z = f2bf(f.z); o.w = f2bf(f.w);
    *(ushort4*)(out + i) = o;
  }
}

__global__ void fill_ones_kernel(unsigned short* __restrict__ p, long n){
  long i = (long)blockIdx.x * blockDim.x + threadIdx.x;
  if (i < n) p[i] = 0x3F80;   // bf16 1.0
}

// ---------------- k_cat = [bf16(k_c) | rope(k_pe)] : (T, 576) ----------------
__global__ void prep_kcat_kernel(const float* __restrict__ kc, const float* __restrict__ kpe,
                                 const int* __restrict__ pos, const float* __restrict__ cosc,
                                 const float* __restrict__ sinc, unsigned short* __restrict__ kcat){
  int t = blockIdx.x; int tid = threadIdx.x;
  for (int c = tid; c < RANK; c += 256)
    kcat[(long)t * D_QK + c] = f2bf(kc[(long)t * RANK + c]);
  if (tid < 32){
    int p = pos[t];
    float c = cosc[p * 32 + tid], s = sinc[p * 32 + tid];
    float x1 = kpe[(long)t * D_ROPE + tid];
    float x2 = kpe[(long)t * D_ROPE + 32 + tid];
    kcat[(long)t * D_QK + RANK + tid]      = f2bf(x1 * c - x2 * s);
    kcat[(long)t * D_QK + RANK + 32 + tid] = f2bf(x2 * c + x1 * s);
  }
}

// ---------------- Vt = bf16(k_c)^T : (512, T) ----------------
__global__ void transpose_vt_kernel(const float* __restrict__ kc, unsigned short* __restrict__ vt){
  __shared__ unsigned short tile[64][65];
  int bi = blockIdx.x, bj = blockIdx.y, tid = threadIdx.x;
  for (int c = tid; c < 4096; c += 256){
    int i = c >> 6, j = c & 63;
    tile[i][j] = f2bf(kc[(long)(bi * 64 + i) * RANK + bj * 64 + j]);
  }
  __syncthreads();
  for (int c = tid; c < 4096; c += 256){
    int j = c >> 6, i = c & 63;
    vt[(long)(bj * 64 + j) * T_SEQ + bi * 64 + i] = tile[i][j];
  }
}

// ---------------- wukt[h][r][d] = bf16(kvb[h*256+d][r]) ----------------
__global__ void prep_wukt_kernel(const float* __restrict__ kvb, unsigned short* __restrict__ wukt){
  __shared__ unsigned short tile[64][65];
  int h = blockIdx.x, db = blockIdx.y, rb = blockIdx.z, tid = threadIdx.x;
  for (int c = tid; c < 4096; c += 256){
    int i = c >> 6, j = c & 63;   // i: d within 64, j: r within 64
    tile[i][j] = f2bf(kvb[(long)(h * 256 + db * 64 + i) * RANK + rb * 64 + j]);
  }
  __syncthreads();
  for (int c = tid; c < 4096; c += 256){
    int j = c >> 6, i = c & 63;
    wukt[(long)h * RANK * D_NOPE + (long)(rb * 64 + j) * D_NOPE + db * 64 + i] = tile[i][j];
  }
}

// ---------------- rope on q_pe: qf(t, h*192+128..191) -> qcat[h][t][512..575] ----------------
__global__ void rope_q_kernel(const unsigned short* __restrict__ qf, const int* __restrict__ pos,
                              const float* __restrict__ cosc, const float* __restrict__ sinc,
                              unsigned short* __restrict__ qcat){
  int t = blockIdx.x; int tid = threadIdx.x;
  int p = pos[t];
  for (int w = tid; w < 512; w += 256){
    int h = w >> 5, i = w & 31;
    float c = cosc[p * 32 + i], s = sinc[p * 32 + i];
    float x1 = bf2f(qf[(long)t * QF_N + h * 192 + 128 + i]);
    float x2 = bf2f(qf[(long)t * QF_N + h * 192 + 128 + 32 + i]);
    long base = (long)h * T_SEQ * D_QK + (long)t * D_QK + RANK;
    qcat[base + i]      = f2bf(x1 * c - x2 * s);
    qcat[base + 32 + i] = f2bf(x2 * c + x1 * s);
  }
}

// ---------------- generic NT bf16 GEMM: C = A(MxK) * B(NxK)^T (async LDS staging) ----------------
template<int OUT_BF16>
__global__ __launch_bounds__(256, 2) void gemm_nt_kernel(
    const unsigned short* __restrict__ A, long lda, long sA,
    const unsigned short* __restrict__ B, long ldb, long sB,
    void* __restrict__ Cv, long ldc, long sC,
    int M, int N, int K)
{
  const int bz = blockIdx.z;
  A += (long)bz * sA;
  B += (long)bz * sB;
  const int m0 = blockIdx.x * 128;
  const int n0 = blockIdx.y * 128;
  const int tid = threadIdx.x;
  const int lane = tid & 63, wave = tid >> 6;
  const int quad = lane >> 4, l16 = lane & 15;
  const int wm = wave & 1, wn = wave >> 1;

  __shared__ __align__(16) unsigned short As[128 * 32];
  __shared__ __align__(16) unsigned short Bs[128 * 32];

  f32x4 acc[4][4];
  #pragma unroll
  for (int mt = 0; mt < 4; ++mt)
    #pragma unroll
    for (int nt = 0; nt < 4; ++nt)
      acc[mt][nt] = (f32x4){0.f, 0.f, 0.f, 0.f};

  for (int k0 = 0; k0 < K; k0 += 32){
    __syncthreads();
    #pragma unroll
    for (int i = 0; i < 2; ++i){
      int c = i * 256 + tid;
      int row = c >> 2, col = (c & 3) * 8;
      gload_lds16(A + (long)(m0 + row) * lda + k0 + col, &As[c * 8]);
      gload_lds16(B + (long)(n0 + row) * ldb + k0 + col, &Bs[c * 8]);
    }
    __syncthreads();
    bf16x8 af[4], bg[4];
    #pragma unroll
    for (int mt = 0; mt < 4; ++mt) af[mt] = ld_frag(&As[(wm * 64 + mt * 16 + l16) * 32 + quad * 8]);
    #pragma unroll
    for (int nt = 0; nt < 4; ++nt) bg[nt] = ld_frag(&Bs[(wn * 64 + nt * 16 + l16) * 32 + quad * 8]);
    #pragma unroll
    for (int mt = 0; mt < 4; ++mt)
      #pragma unroll
      for (int nt = 0; nt < 4; ++nt)
        acc[mt][nt] = __builtin_amdgcn_mfma_f32_16x16x32_bf16(af[mt], bg[nt], acc[mt][nt], 0, 0, 0);
  }

  if (OUT_BF16){
    unsigned short* C = (unsigned short*)Cv + (long)bz * sC;
    #pragma unroll
    for (int mt = 0; mt < 4; ++mt)
      #pragma unroll
      for (int nt = 0; nt < 4; ++nt)
        #pragma unroll
        for (int r = 0; r < 4; ++r)
          C[(long)(m0 + wm * 64 + mt * 16 + quad * 4 + r) * ldc + n0 + wn * 64 + nt * 16 + l16] =
              f2bf(acc[mt][nt][r]);
  } else {
    float* C = (float*)Cv + (long)bz * sC;
    #pragma unroll
    for (int mt = 0; mt < 4; ++mt)
      #pragma unroll
      for (int nt = 0; nt < 4; ++nt)
        #pragma unroll
        for (int r = 0; r < 4; ++r)
          C[(long)(m0 + wm * 64 + mt * 16 + quad * 4 + r) * ldc + n0 + wn * 64 + nt * 16 + l16] =
              acc[mt][nt][r];
  }
}

// ---------------- causal MQA flash attention ----------------
// Round-3 structure (the no-spill one): grid (NH, 32 tiles, 2 v-halves), 4 waves,
// wave w owns rows t0+16w..+15 (wave-autonomous softmax), oacc = 16 rows x 256 v.
// Round-5 deltas: (1) next K-tile prefetched into VGPRs before QK so its latency
// overlaps QK+softmax+PV (fits: ~225 regs < 256 at 2 waves/SIMD); (2) ones-row
// appended to Vt gives P row-sums via one extra MFMA (deletes 16 sum-shuffles);
// (3) precomputed staging offsets.
__global__ __launch_bounds__(256, 2) void attn_kernel(
    const unsigned short* __restrict__ qcat,
    const unsigned short* __restrict__ kcat,
    const unsigned short* __restrict__ vt,
    unsigned short* __restrict__ olat)
{
  const int h = blockIdx.x;
  const int ti = (int)gridDim.y - 1 - (int)blockIdx.y;   // longest blocks first
  const int vz = blockIdx.z;
  const int t0 = ti * 64;
  const int tid = threadIdx.x;
  const int lane = tid & 63, wave = tid >> 6;
  const int quad = lane >> 4, l16 = lane & 15;
  const int t0w = t0 + wave * 16;

  __shared__ __align__(16) unsigned short Ks[32 * 584];    // stride 584: 2-way-only conflicts
  __shared__ __align__(16) unsigned short Pw[4][16 * 40];  // per-wave P buffer

  const unsigned short* vbase = vt + (long)(vz * 256) * T_SEQ;
  const unsigned short* vones = vt + (long)RANK * T_SEQ;   // row of bf16 1.0

  // per-lane staging offsets, computed once (chunk i covers flat 16B-unit i*256+tid)
  int goff[9], loff[9];
  #pragma unroll
  for (int i = 0; i < 9; ++i){
    int fc = i * 256 + tid;
    int r = fc / 72, c = fc - r * 72;
    goff[i] = r * D_QK + c * 8;
    loff[i] = r * 584 + c * 8;
  }

  // Q fragments in registers (A-layout: m=l16, k=quad*8+j), 18 chunks = 72 VGPRs
  bf16x8 qf[18];
  {
    const unsigned short* qrow = qcat + (long)h * T_SEQ * D_QK + (long)(t0w + l16) * D_QK;
    #pragma unroll
    for (int kk = 0; kk < 18; ++kk) qf[kk] = ld_frag(qrow + kk * 32 + quad * 8);
  }

  f32x4 oacc[16];   // 16 rows x 256 v-dims = 64 regs
  #pragma unroll
  for (int ct = 0; ct < 16; ++ct) oacc[ct] = (f32x4){0.f, 0.f, 0.f, 0.f};
  f32x4 oacc_l = (f32x4){0.f, 0.f, 0.f, 0.f};   // P row-sums via ones-row
  float m_run[4];
  #pragma unroll
  for (int r = 0; r < 4; ++r) m_run[r] = -3e38f;

  const int niter = 2 * (ti + 1);

  // initial stage (VGPR roundtrip)
  {
    uint4 kv[9];
    #pragma unroll
    for (int i = 0; i < 9; ++i) kv[i] = *(const uint4*)(kcat + goff[i]);
    #pragma unroll
    for (int i = 0; i < 9; ++i) *(uint4*)(&Ks[loff[i]]) = kv[i];
  }
  __syncthreads();

  for (int it = 0; it < niter; ++it){
    const int s0 = it * 32;

    // ---- prefetch next K-tile into VGPRs (latency hidden under QK/softmax/PV) ----
    uint4 kv[9];
    const bool more = (it + 1 < niter);
    if (more){
      const unsigned short* kb = kcat + (long)(s0 + 32) * D_QK;
      #pragma unroll
      for (int i = 0; i < 9; ++i) kv[i] = *(const uint4*)(kb + goff[i]);
    }

    // ---- S = Q K^T (16 rows x 32 keys per wave) ----
    f32x4 sacc0 = (f32x4){0.f,0.f,0.f,0.f}, sacc1 = (f32x4){0.f,0.f,0.f,0.f};
    #pragma unroll
    for (int kk = 0; kk < 18; ++kk){
      bf16x8 b0 = ld_frag(&Ks[l16 * 584 + kk * 32 + quad * 8]);
      bf16x8 b1 = ld_frag(&Ks[(16 + l16) * 584 + kk * 32 + quad * 8]);
      sacc0 = __builtin_amdgcn_mfma_f32_16x16x32_bf16(qf[kk], b0, sacc0, 0, 0, 0);
      sacc1 = __builtin_amdgcn_mfma_f32_16x16x32_bf16(qf[kk], b1, sacc1, 0, 0, 0);
    }
    __syncthreads();     // (a) all waves done reading Ks

    // ---- wave-local online softmax ----
    float sv[2][4], mr[4];
    #pragma unroll
    for (int r = 0; r < 4; ++r){
      int row = t0w + quad * 4 + r;
      float v0 = sacc0[r] * ATT_SCALE;
      float v1 = sacc1[r] * ATT_SCALE;
      if (s0 + l16 > row)      v0 = -3e38f;
      if (s0 + 16 + l16 > row) v1 = -3e38f;
      sv[0][r] = v0; sv[1][r] = v1; mr[r] = fmaxf(v0, v1);
    }
    #pragma unroll
    for (int d = 1; d < 16; d <<= 1)
      #pragma unroll
      for (int r = 0; r < 4; ++r) mr[r] = fmaxf(mr[r], __shfl_xor(mr[r], d, 64));
    float alpha[4];
    #pragma unroll
    for (int r = 0; r < 4; ++r){
      float mn = fmaxf(m_run[r], mr[r]);
      alpha[r] = __expf(m_run[r] - mn);
      m_run[r] = mn;
      float p0 = __expf(sv[0][r] - mn);
      float p1 = __expf(sv[1][r] - mn);
      Pw[wave][(quad * 4 + r) * 40 + l16]      = f2bf(p0);
      Pw[wave][(quad * 4 + r) * 40 + 16 + l16] = f2bf(p1);
    }

    // rescale O (+ row-sum accumulator)
    #pragma unroll
    for (int ct = 0; ct < 16; ++ct)
      #pragma unroll
      for (int r = 0; r < 4; ++r) oacc[ct][r] *= alpha[r];
    #pragma unroll
    for (int r = 0; r < 4; ++r) oacc_l[r] *= alpha[r];

    // P write -> A-frag read is wave-local cross-lane: drain DS pipe
    __builtin_amdgcn_s_waitcnt(0xC07F);   // lgkmcnt(0)

    bf16x8 pa = ld_frag(&Pw[wave][l16 * 40 + quad * 8]);
    #pragma unroll
    for (int ct = 0; ct < 16; ++ct){
      bf16x8 bv = ld_frag(vbase + (long)(ct * 16 + l16) * T_SEQ + s0 + quad * 8);
      oacc[ct] = __builtin_amdgcn_mfma_f32_16x16x32_bf16(pa, bv, oacc[ct], 0, 0, 0);
    }
    {
      bf16x8 bo = ld_frag(vones + s0 + quad * 8);   // broadcast row of ones
      oacc_l = __builtin_amdgcn_mfma_f32_16x16x32_bf16(pa, bo, oacc_l, 0, 0, 0);
    }

    // ---- write prefetched tile into Ks ----
    if (more){
      #pragma unroll
      for (int i = 0; i < 9; ++i) *(uint4*)(&Ks[loff[i]]) = kv[i];
    }
    __syncthreads();     // (b) next tile staged
  }

  // ---- epilogue ----
  float inv[4];
  #pragma unroll
  for (int r = 0; r < 4; ++r) inv[r] = 1.0f / oacc_l[r];
  #pragma unroll
  for (int ct = 0; ct < 16; ++ct)
    #pragma unroll
    for (int r = 0; r < 4; ++r){
      int row = t0w + quad * 4 + r;
      olat[(long)h * T_SEQ * RANK + (long)row * RANK + vz * 256 + ct * 16 + l16] =
          f2bf(oacc[ct][r] * inv[r]);
    }
}

// ---------------- host launcher ----------------
extern "C" void kernel_launch(void* const* d_in, const int* in_sizes, int n_in,
                              void* d_out, int out_size, void* d_ws, size_t ws_size,
                              hipStream_t stream){
  const float* q    = (const float*)d_in[0];
  const float* kc   = (const float*)d_in[1];
  const float* kpe  = (const float*)d_in[2];
  const int*   pos  = (const int*)d_in[3];
  const float* wq   = (const float*)d_in[4];
  const float* kvb  = (const float*)d_in[5];
  const float* wo   = (const float*)d_in[6];
  const float* cosc = (const float*)d_in[7];
  const float* sinc = (const float*)d_in[8];
  float* out = (float*)d_out;

  char* ws = (char*)d_ws;
  size_t off = 0;
  auto alloc_us = [&](long nelem) -> unsigned short* {
    unsigned short* p = (unsigned short*)(ws + off);
    off += ((size_t)nelem * 2 + 255) & ~(size_t)255;
    return p;
  };
  unsigned short* q_bf   = alloc_us((long)T_SEQ * D_QIN);          // 2048x1536
  unsigned short* wq_bf  = alloc_us((long)QF_N * D_QIN);           // 3072x1536
  unsigned short* kvb_bf = alloc_us((long)NH * 256 * RANK);        // 4096x512
  unsigned short* wukt   = alloc_us((long)NH * RANK * D_NOPE);     // 16x512x128
  unsigned short* wo_bf  = alloc_us((long)D_HID * NH * D_V);       // 7168x2048
  unsigned short* kcat   = alloc_us((long)T_SEQ * D_QK);           // 2048x576
  unsigned short* vt     = alloc_us((long)(RANK + 1) * T_SEQ);     // 513x2048 (row 512 = ones)
  unsigned short* qf_bf  = alloc_us((long)T_SEQ * QF_N);           // 2048x3072
  unsigned short* qcat   = alloc_us((long)NH * T_SEQ * D_QK);      // 16x2048x576
  unsigned short* olat   = alloc_us((long)NH * T_SEQ * RANK);      // 16x2048x512
  unsigned short* o_mid  = alloc_us((long)T_SEQ * NH * D_V);       // 2048x2048

  // conversions
  {
    long n;
    n = (long)T_SEQ * D_QIN;
    cvt_bf16_kernel<<<dim3((unsigned)(n / 1024)), 256, 0, stream>>>(q, q_bf, n);
    n = (long)QF_N * D_QIN;
    cvt_bf16_kernel<<<dim3((unsigned)(n / 1024)), 256, 0, stream>>>(wq, wq_bf, n);
    n = (long)NH * 256 * RANK;
    cvt_bf16_kernel<<<dim3((unsigned)(n / 1024)), 256, 0, stream>>>(kvb, kvb_bf, n);
    n = (long)D_HID * NH * D_V;
    cvt_bf16_kernel<<<dim3((unsigned)(n / 1024)), 256, 0, stream>>>(wo, wo_bf, n);
  }
  prep_kcat_kernel<<<dim3(T_SEQ), 256, 0, stream>>>(kc, kpe, pos, cosc, sinc, kcat);
  transpose_vt_kernel<<<dim3(T_SEQ / 64, RANK / 64), 256, 0, stream>>>(kc, vt);
  fill_ones_kernel<<<dim3(T_SEQ / 256), 256, 0, stream>>>(vt + (long)RANK * T_SEQ, T_SEQ);
  prep_wukt_kernel<<<dim3(NH, D_NOPE / 64, RANK / 64), 256, 0, stream>>>(kvb, wukt);

  // G1: qf = q @ wq^T  (2048 x 3072, K=1536), bf16 out
  gemm_nt_kernel<1><<<dim3(T_SEQ / 128, QF_N / 128), 256, 0, stream>>>(
      q_bf, D_QIN, 0, wq_bf, D_QIN, 0, (void*)qf_bf, QF_N, 0, T_SEQ, QF_N, D_QIN);

  rope_q_kernel<<<dim3(T_SEQ), 256, 0, stream>>>(qf_bf, pos, cosc, sinc, qcat);

  // G2 (batched over heads): qcat[h][:, 0:512] = q_nope_h @ wukt_h^T  (2048x512, K=128)
  gemm_nt_kernel<1><<<dim3(T_SEQ / 128, RANK / 128, NH), 256, 0, stream>>>(
      qf_bf, QF_N, 192,
      wukt, D_NOPE, (long)RANK * D_NOPE,
      (void*)qcat, D_QK, (long)T_SEQ * D_QK,
      T_SEQ, RANK, D_NOPE);

  // attention: grid (head, tile, v-half), longest tiles dispatched first
  attn_kernel<<<dim3(NH, T_SEQ / 64, 2), 256, 0, stream>>>(qcat, kcat, vt, olat);

  // G3 (batched): o_mid[:, h*128:(h+1)*128] = olat_h @ w_uv_h^T  (2048x128, K=512)
  gemm_nt_kernel<1><<<dim3(T_SEQ / 128, D_V / 128, NH), 256, 0, stream>>>(
      olat, RANK, (long)T_SEQ * RANK,
      kvb_bf + (long)128 * RANK, RANK, (long)256 * RANK,
      (void*)o_mid, (long)NH * D_V, (long)D_V,
      T_SEQ, D_V, RANK);

  // G4: out = o_mid @ wo^T  (2048 x 7168, K=2048), fp32 out
  gemm_nt_kernel<0><<<dim3(T_SEQ / 128, D_HID / 128), 256, 0, stream>>>(
      o_mid, (long)NH * D_V, 0, wo_bf, (long)NH * D_V, 0, (void*)out, D_HID, 0,
      T_SEQ, D_HID, (long)NH * D_V);
}

// Round 6
// 654.983 us; speedup vs baseline: 2.1825x; 1.3257x over previous
//
#include <hip/hip_runtime.h>

#define T_SEQ 2048
#define NH    16
#define D_NOPE 128
#define D_ROPE 64
#define D_V   128
#define RANK  512
#define D_QIN 1536
#define D_HID 7168
#define D_QK  576           // RANK + D_ROPE
#define QF_N  3072          // NH*(D_NOPE+D_ROPE)
#define ATT_SCALE 0.07216878364870322f   // (192)^-0.5

typedef float  f32x4  __attribute__((ext_vector_type(4)));
typedef __bf16 bf16x8 __attribute__((ext_vector_type(8)));

__device__ __forceinline__ unsigned short f2bf(float x){
  union{float f; unsigned u;} v; v.f = x;
  return (unsigned short)((v.u + 0x7fffu + ((v.u >> 16) & 1u)) >> 16);
}
__device__ __forceinline__ float bf2f(unsigned short b){
  union{unsigned u; float f;} v; v.u = ((unsigned)b) << 16; return v.f;
}
__device__ __forceinline__ bf16x8 ld_frag(const unsigned short* p){
  union{ uint4 u; bf16x8 v; } w; w.u = *(const uint4*)p; return w.v;
}
// async global->LDS, 16B per lane; LDS side must be uniform + lane*16.
__device__ __forceinline__ void gload_lds16(const unsigned short* g, unsigned short* l){
  __builtin_amdgcn_global_load_lds(
      (const __attribute__((address_space(1))) unsigned int*)g,
      (__attribute__((address_space(3))) unsigned int*)l, 16, 0, 0);
}

// ---------------- fp32 -> bf16 bulk convert ----------------
__global__ void cvt_bf16_kernel(const float* __restrict__ in, unsigned short* __restrict__ out, long n){
  long i = ((long)blockIdx.x * blockDim.x + threadIdx.x) * 4;
  if (i + 3 < n){
    float4 f = *(const float4*)(in + i);
    ushort4 o; o.x = f2bf(f.x); o.y = f2bf(f.y); o.z = f2bf(f.z); o.w = f2bf(f.w);
    *(ushort4*)(out + i) = o;
  }
}

__global__ void fill_ones_kernel(unsigned short* __restrict__ p, long n){
  long i = (long)blockIdx.x * blockDim.x + threadIdx.x;
  if (i < n) p[i] = 0x3F80;   // bf16 1.0
}

// ---------------- k_cat = [bf16(k_c) | rope(k_pe)] : (T, 576) ----------------
__global__ void prep_kcat_kernel(const float* __restrict__ kc, const float* __restrict__ kpe,
                                 const int* __restrict__ pos, const float* __restrict__ cosc,
                                 const float* __restrict__ sinc, unsigned short* __restrict__ kcat){
  int t = blockIdx.x; int tid = threadIdx.x;
  for (int c = tid; c < RANK; c += 256)
    kcat[(long)t * D_QK + c] = f2bf(kc[(long)t * RANK + c]);
  if (tid < 32){
    int p = pos[t];
    float c = cosc[p * 32 + tid], s = sinc[p * 32 + tid];
    float x1 = kpe[(long)t * D_ROPE + tid];
    float x2 = kpe[(long)t * D_ROPE + 32 + tid];
    kcat[(long)t * D_QK + RANK + tid]      = f2bf(x1 * c - x2 * s);
    kcat[(long)t * D_QK + RANK + 32 + tid] = f2bf(x2 * c + x1 * s);
  }
}

// ---------------- Vt = bf16(k_c)^T : (512, T) ----------------
__global__ void transpose_vt_kernel(const float* __restrict__ kc, unsigned short* __restrict__ vt){
  __shared__ unsigned short tile[64][65];
  int bi = blockIdx.x, bj = blockIdx.y, tid = threadIdx.x;
  for (int c = tid; c < 4096; c += 256){
    int i = c >> 6, j = c & 63;
    tile[i][j] = f2bf(kc[(long)(bi * 64 + i) * RANK + bj * 64 + j]);
  }
  __syncthreads();
  for (int c = tid; c < 4096; c += 256){
    int j = c >> 6, i = c & 63;
    vt[(long)(bj * 64 + j) * T_SEQ + bi * 64 + i] = tile[i][j];
  }
}

// ---------------- wukt[h][r][d] = bf16(kvb[h*256+d][r]) ----------------
__global__ void prep_wukt_kernel(const float* __restrict__ kvb, unsigned short* __restrict__ wukt){
  __shared__ unsigned short tile[64][65];
  int h = blockIdx.x, db = blockIdx.y, rb = blockIdx.z, tid = threadIdx.x;
  for (int c = tid; c < 4096; c += 256){
    int i = c >> 6, j = c & 63;   // i: d within 64, j: r within 64
    tile[i][j] = f2bf(kvb[(long)(h * 256 + db * 64 + i) * RANK + rb * 64 + j]);
  }
  __syncthreads();
  for (int c = tid; c < 4096; c += 256){
    int j = c >> 6, i = c & 63;
    wukt[(long)h * RANK * D_NOPE + (long)(rb * 64 + j) * D_NOPE + db * 64 + i] = tile[i][j];
  }
}

// ---------------- rope on q_pe: qf(t, h*192+128..191) -> qcat[h][t][512..575] ----------------
__global__ void rope_q_kernel(const unsigned short* __restrict__ qf, const int* __restrict__ pos,
                              const float* __restrict__ cosc, const float* __restrict__ sinc,
                              unsigned short* __restrict__ qcat){
  int t = blockIdx.x; int tid = threadIdx.x;
  int p = pos[t];
  for (int w = tid; w < 512; w += 256){
    int h = w >> 5, i = w & 31;
    float c = cosc[p * 32 + i], s = sinc[p * 32 + i];
    float x1 = bf2f(qf[(long)t * QF_N + h * 192 + 128 + i]);
    float x2 = bf2f(qf[(long)t * QF_N + h * 192 + 128 + 32 + i]);
    long base = (long)h * T_SEQ * D_QK + (long)t * D_QK + RANK;
    qcat[base + i]      = f2bf(x1 * c - x2 * s);
    qcat[base + 32 + i] = f2bf(x2 * c + x1 * s);
  }
}

// ---------------- generic NT bf16 GEMM: C = A(MxK) * B(NxK)^T (async LDS staging) ----------------
template<int OUT_BF16>
__global__ __launch_bounds__(256, 2) void gemm_nt_kernel(
    const unsigned short* __restrict__ A, long lda, long sA,
    const unsigned short* __restrict__ B, long ldb, long sB,
    void* __restrict__ Cv, long ldc, long sC,
    int M, int N, int K)
{
  const int bz = blockIdx.z;
  A += (long)bz * sA;
  B += (long)bz * sB;
  const int m0 = blockIdx.x * 128;
  const int n0 = blockIdx.y * 128;
  const int tid = threadIdx.x;
  const int lane = tid & 63, wave = tid >> 6;
  const int quad = lane >> 4, l16 = lane & 15;
  const int wm = wave & 1, wn = wave >> 1;

  __shared__ __align__(16) unsigned short As[128 * 32];
  __shared__ __align__(16) unsigned short Bs[128 * 32];

  f32x4 acc[4][4];
  #pragma unroll
  for (int mt = 0; mt < 4; ++mt)
    #pragma unroll
    for (int nt = 0; nt < 4; ++nt)
      acc[mt][nt] = (f32x4){0.f, 0.f, 0.f, 0.f};

  for (int k0 = 0; k0 < K; k0 += 32){
    __syncthreads();
    #pragma unroll
    for (int i = 0; i < 2; ++i){
      int c = i * 256 + tid;
      int row = c >> 2, col = (c & 3) * 8;
      gload_lds16(A + (long)(m0 + row) * lda + k0 + col, &As[c * 8]);
      gload_lds16(B + (long)(n0 + row) * ldb + k0 + col, &Bs[c * 8]);
    }
    __syncthreads();
    bf16x8 af[4], bg[4];
    #pragma unroll
    for (int mt = 0; mt < 4; ++mt) af[mt] = ld_frag(&As[(wm * 64 + mt * 16 + l16) * 32 + quad * 8]);
    #pragma unroll
    for (int nt = 0; nt < 4; ++nt) bg[nt] = ld_frag(&Bs[(wn * 64 + nt * 16 + l16) * 32 + quad * 8]);
    #pragma unroll
    for (int mt = 0; mt < 4; ++mt)
      #pragma unroll
      for (int nt = 0; nt < 4; ++nt)
        acc[mt][nt] = __builtin_amdgcn_mfma_f32_16x16x32_bf16(af[mt], bg[nt], acc[mt][nt], 0, 0, 0);
  }

  if (OUT_BF16){
    unsigned short* C = (unsigned short*)Cv + (long)bz * sC;
    #pragma unroll
    for (int mt = 0; mt < 4; ++mt)
      #pragma unroll
      for (int nt = 0; nt < 4; ++nt)
        #pragma unroll
        for (int r = 0; r < 4; ++r)
          C[(long)(m0 + wm * 64 + mt * 16 + quad * 4 + r) * ldc + n0 + wn * 64 + nt * 16 + l16] =
              f2bf(acc[mt][nt][r]);
  } else {
    float* C = (float*)Cv + (long)bz * sC;
    #pragma unroll
    for (int mt = 0; mt < 4; ++mt)
      #pragma unroll
      for (int nt = 0; nt < 4; ++nt)
        #pragma unroll
        for (int r = 0; r < 4; ++r)
          C[(long)(m0 + wm * 64 + mt * 16 + quad * 4 + r) * ldc + n0 + wn * 64 + nt * 16 + l16] =
              acc[mt][nt][r];
  }
}

// ---------------- causal MQA flash attention ----------------
// Grid (NH, 32 tiles, 2 v-halves); 4 waves; wave w owns rows t0+16w..+15
// (wave-autonomous softmax). oacc = 16 rows x 256 v-dims.
// K tile staged via global_load_lds DMA (no VGPR transit -> no spill) into a
// DOUBLE-BUFFERED SWIZZLED layout: LDS unit u of row r holds column-unit
// c=(u&~7)|((u-r)&7)  (global side of the DMA is per-lane arbitrary, LDS side
// is the required uniform+lane*16). Readers: u=(c&~7)|((c+r)&7) -> bank group
// (c+r)&7 spreads 16 rows evenly = conflict-minimal, same as padding.
// One barrier per iter: its implicit vmcnt(0) drain retires the next-tile DMA.
__global__ __launch_bounds__(256, 2) void attn_kernel(
    const unsigned short* __restrict__ qcat,
    const unsigned short* __restrict__ kcat,
    const unsigned short* __restrict__ vt,
    unsigned short* __restrict__ olat)
{
  const int h = blockIdx.x;
  const int ti = (int)gridDim.y - 1 - (int)blockIdx.y;   // longest blocks first
  const int vz = blockIdx.z;
  const int t0 = ti * 64;
  const int tid = threadIdx.x;
  const int lane = tid & 63, wave = tid >> 6;
  const int quad = lane >> 4, l16 = lane & 15;
  const int t0w = t0 + wave * 16;

  __shared__ __align__(16) unsigned short Ks[2][32 * 576];   // swizzled, DMA-staged
  __shared__ __align__(16) unsigned short Pw[4][16 * 40];    // per-wave P buffer

  const unsigned short* vbase = vt + (long)(vz * 256) * T_SEQ;
  const unsigned short* vones = vt + (long)RANK * T_SEQ;     // row of bf16 1.0

  // staging map: LDS unit fc=i*256+tid -> row r=fc/72, u=fc%72, global col-unit
  // c=(u&~7)|((u-r)&7). 9 ints of per-lane global offset, no per-iter div/mod.
  int goffK[9];
  #pragma unroll
  for (int i = 0; i < 9; ++i){
    int fc = i * 256 + tid;
    int r = fc / 72, u = fc - r * 72;
    int c = (u & ~7) | ((u - r) & 7);
    goffK[i] = r * D_QK + c * 8;
  }

  // Q fragments in registers (A-layout: m=l16, k=quad*8+j), 18 chunks = 72 VGPRs
  bf16x8 qf[18];
  {
    const unsigned short* qrow = qcat + (long)h * T_SEQ * D_QK + (long)(t0w + l16) * D_QK;
    #pragma unroll
    for (int kk = 0; kk < 18; ++kk) qf[kk] = ld_frag(qrow + kk * 32 + quad * 8);
  }

  f32x4 oacc[16];   // 16 rows x 256 v-dims
  #pragma unroll
  for (int ct = 0; ct < 16; ++ct) oacc[ct] = (f32x4){0.f, 0.f, 0.f, 0.f};
  f32x4 oacc_l = (f32x4){0.f, 0.f, 0.f, 0.f};   // P row-sums via ones-row
  float m_run[4];
  #pragma unroll
  for (int r = 0; r < 4; ++r) m_run[r] = -3e38f;

  const int niter = 2 * (ti + 1);

  // prologue: DMA tile 0 into buf 0
  #pragma unroll
  for (int i = 0; i < 9; ++i)
    gload_lds16(kcat + goffK[i], &Ks[0][(i * 256 + tid) * 8]);
  __syncthreads();   // implicit vmcnt(0) drain

  for (int it = 0; it < niter; ++it){
    const int s0 = it * 32;
    const int cur = it & 1;

    // ---- async DMA next K-tile into the other buffer (zero VGPR cost) ----
    if (it + 1 < niter){
      const unsigned short* kb = kcat + (long)(s0 + 32) * D_QK;
      #pragma unroll
      for (int i = 0; i < 9; ++i)
        gload_lds16(kb + goffK[i], &Ks[cur ^ 1][(i * 256 + tid) * 8]);
    }

    // ---- S = Q K^T (16 rows x 32 keys per wave), swizzled B-frag reads ----
    f32x4 sacc0 = (f32x4){0.f,0.f,0.f,0.f}, sacc1 = (f32x4){0.f,0.f,0.f,0.f};
    #pragma unroll
    for (int kk = 0; kk < 18; ++kk){
      const int c = kk * 4 + quad;
      const int chi = c & ~7;
      int u0 = chi | ((c + l16) & 7);          // row l16
      int u1 = chi | ((c + 16 + l16) & 7);     // row 16+l16
      bf16x8 b0 = ld_frag(&Ks[cur][l16 * 576 + u0 * 8]);
      bf16x8 b1 = ld_frag(&Ks[cur][(16 + l16) * 576 + u1 * 8]);
      sacc0 = __builtin_amdgcn_mfma_f32_16x16x32_bf16(qf[kk], b0, sacc0, 0, 0, 0);
      sacc1 = __builtin_amdgcn_mfma_f32_16x16x32_bf16(qf[kk], b1, sacc1, 0, 0, 0);
    }

    // ---- wave-local online softmax ----
    float sv[2][4], mr[4];
    #pragma unroll
    for (int r = 0; r < 4; ++r){
      int row = t0w + quad * 4 + r;
      float v0 = sacc0[r] * ATT_SCALE;
      float v1 = sacc1[r] * ATT_SCALE;
      if (s0 + l16 > row)      v0 = -3e38f;
      if (s0 + 16 + l16 > row) v1 = -3e38f;
      sv[0][r] = v0; sv[1][r] = v1; mr[r] = fmaxf(v0, v1);
    }
    #pragma unroll
    for (int d = 1; d < 16; d <<= 1)
      #pragma unroll
      for (int r = 0; r < 4; ++r) mr[r] = fmaxf(mr[r], __shfl_xor(mr[r], d, 64));
    float alpha[4];
    #pragma unroll
    for (int r = 0; r < 4; ++r){
      float mn = fmaxf(m_run[r], mr[r]);
      alpha[r] = __expf(m_run[r] - mn);
      m_run[r] = mn;
      float p0 = __expf(sv[0][r] - mn);
      float p1 = __expf(sv[1][r] - mn);
      Pw[wave][(quad * 4 + r) * 40 + l16]      = f2bf(p0);
      Pw[wave][(quad * 4 + r) * 40 + 16 + l16] = f2bf(p1);
    }

    // rescale O (+ row-sum accumulator)
    #pragma unroll
    for (int ct = 0; ct < 16; ++ct)
      #pragma unroll
      for (int r = 0; r < 4; ++r) oacc[ct][r] *= alpha[r];
    #pragma unroll
    for (int r = 0; r < 4; ++r) oacc_l[r] *= alpha[r];

    // P write -> A-frag read is wave-local cross-lane: drain DS pipe
    __builtin_amdgcn_s_waitcnt(0xC07F);   // lgkmcnt(0)

    bf16x8 pa = ld_frag(&Pw[wave][l16 * 40 + quad * 8]);
    #pragma unroll
    for (int ct = 0; ct < 16; ++ct){
      bf16x8 bv = ld_frag(vbase + (long)(ct * 16 + l16) * T_SEQ + s0 + quad * 8);
      oacc[ct] = __builtin_amdgcn_mfma_f32_16x16x32_bf16(pa, bv, oacc[ct], 0, 0, 0);
    }
    {
      bf16x8 bo = ld_frag(vones + s0 + quad * 8);   // broadcast row of ones
      oacc_l = __builtin_amdgcn_mfma_f32_16x16x32_bf16(pa, bo, oacc_l, 0, 0, 0);
    }

    // one barrier/iter: implicit vmcnt(0) retires next-tile DMA; all waves
    // are done reading Ks[cur] so it can be DMA'd into next iteration.
    __syncthreads();
  }

  // ---- epilogue ----
  float inv[4];
  #pragma unroll
  for (int r = 0; r < 4; ++r) inv[r] = 1.0f / oacc_l[r];
  #pragma unroll
  for (int ct = 0; ct < 16; ++ct)
    #pragma unroll
    for (int r = 0; r < 4; ++r){
      int row = t0w + quad * 4 + r;
      olat[(long)h * T_SEQ * RANK + (long)row * RANK + vz * 256 + ct * 16 + l16] =
          f2bf(oacc[ct][r] * inv[r]);
    }
}

// ---------------- host launcher ----------------
extern "C" void kernel_launch(void* const* d_in, const int* in_sizes, int n_in,
                              void* d_out, int out_size, void* d_ws, size_t ws_size,
                              hipStream_t stream){
  const float* q    = (const float*)d_in[0];
  const float* kc   = (const float*)d_in[1];
  const float* kpe  = (const float*)d_in[2];
  const int*   pos  = (const int*)d_in[3];
  const float* wq   = (const float*)d_in[4];
  const float* kvb  = (const float*)d_in[5];
  const float* wo   = (const float*)d_in[6];
  const float* cosc = (const float*)d_in[7];
  const float* sinc = (const float*)d_in[8];
  float* out = (float*)d_out;

  char* ws = (char*)d_ws;
  size_t off = 0;
  auto alloc_us = [&](long nelem) -> unsigned short* {
    unsigned short* p = (unsigned short*)(ws + off);
    off += ((size_t)nelem * 2 + 255) & ~(size_t)255;
    return p;
  };
  unsigned short* q_bf   = alloc_us((long)T_SEQ * D_QIN);          // 2048x1536
  unsigned short* wq_bf  = alloc_us((long)QF_N * D_QIN);           // 3072x1536
  unsigned short* kvb_bf = alloc_us((long)NH * 256 * RANK);        // 4096x512
  unsigned short* wukt   = alloc_us((long)NH * RANK * D_NOPE);     // 16x512x128
  unsigned short* wo_bf  = alloc_us((long)D_HID * NH * D_V);       // 7168x2048
  unsigned short* kcat   = alloc_us((long)T_SEQ * D_QK);           // 2048x576
  unsigned short* vt     = alloc_us((long)(RANK + 1) * T_SEQ);     // 513x2048 (row 512 = ones)
  unsigned short* qf_bf  = alloc_us((long)T_SEQ * QF_N);           // 2048x3072
  unsigned short* qcat   = alloc_us((long)NH * T_SEQ * D_QK);      // 16x2048x576
  unsigned short* olat   = alloc_us((long)NH * T_SEQ * RANK);     // 16x2048x512
  unsigned short* o_mid  = alloc_us((long)T_SEQ * NH * D_V);       // 2048x2048

  // conversions
  {
    long n;
    n = (long)T_SEQ * D_QIN;
    cvt_bf16_kernel<<<dim3((unsigned)(n / 1024)), 256, 0, stream>>>(q, q_bf, n);
    n = (long)QF_N * D_QIN;
    cvt_bf16_kernel<<<dim3((unsigned)(n / 1024)), 256, 0, stream>>>(wq, wq_bf, n);
    n = (long)NH * 256 * RANK;
    cvt_bf16_kernel<<<dim3((unsigned)(n / 1024)), 256, 0, stream>>>(kvb, kvb_bf, n);
    n = (long)D_HID * NH * D_V;
    cvt_bf16_kernel<<<dim3((unsigned)(n / 1024)), 256, 0, stream>>>(wo, wo_bf, n);
  }
  prep_kcat_kernel<<<dim3(T_SEQ), 256, 0, stream>>>(kc, kpe, pos, cosc, sinc, kcat);
  transpose_vt_kernel<<<dim3(T_SEQ / 64, RANK / 64), 256, 0, stream>>>(kc, vt);
  fill_ones_kernel<<<dim3(T_SEQ / 256), 256, 0, stream>>>(vt + (long)RANK * T_SEQ, T_SEQ);
  prep_wukt_kernel<<<dim3(NH, D_NOPE / 64, RANK / 64), 256, 0, stream>>>(kvb, wukt);

  // G1: qf = q @ wq^T  (2048 x 3072, K=1536), bf16 out
  gemm_nt_kernel<1><<<dim3(T_SEQ / 128, QF_N / 128), 256, 0, stream>>>(
      q_bf, D_QIN, 0, wq_bf, D_QIN, 0, (void*)qf_bf, QF_N, 0, T_SEQ, QF_N, D_QIN);

  rope_q_kernel<<<dim3(T_SEQ), 256, 0, stream>>>(qf_bf, pos, cosc, sinc, qcat);

  // G2 (batched over heads): qcat[h][:, 0:512] = q_nope_h @ wukt_h^T  (2048x512, K=128)
  gemm_nt_kernel<1><<<dim3(T_SEQ / 128, RANK / 128, NH), 256, 0, stream>>>(
      qf_bf, QF_N, 192,
      wukt, D_NOPE, (long)RANK * D_NOPE,
      (void*)qcat, D_QK, (long)T_SEQ * D_QK,
      T_SEQ, RANK, D_NOPE);

  // attention: grid (head, tile, v-half), longest tiles dispatched first
  attn_kernel<<<dim3(NH, T_SEQ / 64, 2), 256, 0, stream>>>(qcat, kcat, vt, olat);

  // G3 (batched): o_mid[:, h*128:(h+1)*128] = olat_h @ w_uv_h^T  (2048x128, K=512)
  gemm_nt_kernel<1><<<dim3(T_SEQ / 128, D_V / 128, NH), 256, 0, stream>>>(
      olat, RANK, (long)T_SEQ * RANK,
      kvb_bf + (long)128 * RANK, RANK, (long)256 * RANK,
      (void*)o_mid, (long)NH * D_V, (long)D_V,
      T_SEQ, D_V, RANK);

  // G4: out = o_mid @ wo^T  (2048 x 7168, K=2048), fp32 out
  gemm_nt_kernel<0><<<dim3(T_SEQ / 128, D_HID / 128), 256, 0, stream>>>(
      o_mid, (long)NH * D_V, 0, wo_bf, (long)NH * D_V, 0, (void*)out, D_HID, 0,
      T_SEQ, D_HID, (long)NH * D_V);
}